// Round 6
// baseline (264.386 us; speedup 1.0000x reference)
//
#include <hip/hip_runtime.h>
#include <math.h>

#define EPSV 1e-5f
#define SCALE_W 0.0441941738241592f   /* 1/sqrt(512) */
#define GAIN_R 1.4142135623730951f    /* sqrt(2) */

typedef __attribute__((ext_vector_type(8))) short bf16x8;
typedef __attribute__((ext_vector_type(4))) float f32x4;

static __device__ __forceinline__ unsigned short f2bf(float f) {
  union { float f; unsigned int u; } v; v.f = f;
  unsigned int r = v.u + 0x7FFFu + ((v.u >> 16) & 1u);   // RNE
  return (unsigned short)(r >> 16);
}

#define GLD_LDS16(gsrc, ldst)                                                                      \
  __builtin_amdgcn_global_load_lds((const __attribute__((address_space(1))) unsigned int*)(gsrc),  \
                                   (__attribute__((address_space(3))) unsigned int*)(ldst), 16, 0, 0)

// lgkm-only barrier: does NOT drain vmcnt -> gload_lds/x prefetches survive
#define LBAR() do {                                          \
  asm volatile("s_waitcnt lgkmcnt(0)" ::: "memory");         \
  __builtin_amdgcn_sched_barrier(0);                         \
  __builtin_amdgcn_s_barrier();                              \
  __builtin_amdgcn_sched_barrier(0);                         \
} while (0)

// counted drain: completes current step's 4 B-gloads + L(u-1); leaves 5 newest in flight
#define VMW5() do {                                          \
  asm volatile("s_waitcnt vmcnt(5)" ::: "memory");           \
  __builtin_amdgcn_sched_barrier(0);                         \
} while (0)

// ---------------- pre-kernel: b = expmap0(bias), y2 = ||b||^2 ----------------
__global__ void bias_expmap_k(const float* __restrict__ bias, float* __restrict__ bexp,
                              float* __restrict__ y2out) {
  __shared__ float part[8];
  int t = threadIdx.x;
  float bv = bias[t];
  float s = bv * bv;
  s += __shfl_xor(s, 1);  s += __shfl_xor(s, 2);  s += __shfl_xor(s, 4);
  s += __shfl_xor(s, 8);  s += __shfl_xor(s, 16); s += __shfl_xor(s, 32);
  if ((t & 63) == 0) part[t >> 6] = s;
  __syncthreads();
  float tot = 0.f;
#pragma unroll
  for (int i = 0; i < 8; ++i) tot += part[i];
  float un = fmaxf(sqrtf(tot), EPSV);
  float th = tanhf(un);
  bexp[t] = th * bv / un;
  if (t == 0) *y2out = th * th;
}

// ---------------- pre-kernel: pack weight -> bf16 fragments, SCALE baked ----
// chunk = (ks*32 + colhi); within chunk ushort idx = (lgr*16+l15)*8 + j.
__global__ void pack_weight_k(const float* __restrict__ w, unsigned short* __restrict__ wsB) {
  int e = blockIdx.x * 256 + threadIdx.x;   // 0..262143
  int o = e >> 9;          // output col (row of W)
  int k = e & 511;
  int ks = k >> 5, kk = k & 31;
  int lgr = kk >> 3, j = kk & 7;
  int colhi = o >> 4, l15 = o & 15;
  int dst = ((ks * 32 + colhi) * 64 + lgr * 16 + l15) * 8 + j;
  wsB[dst] = f2bf(w[e] * SCALE_W);
}

// ---------------- main fused kernel ----------------
// 512 thr / 8 waves, BM=64, wave tile 64x64 (mf=4,nf=4, acc=64).
// A: 4-slot ring of [64 rows][72 B] slices (32 k each). B: 2 x 32 KB via gload_lds.
#define ASLOT 4608       /* 64*72 */
#define BOFF_L 18432     /* 4*ASLOT */
#define SCR 83968        /* BOFF_L + 2*32768 */
#define SMEMSZ 88832

__global__ __launch_bounds__(512, 2)
void hyp_main_k(const float* __restrict__ x, const unsigned short* __restrict__ wsB,
                const float* __restrict__ bexp, const float* __restrict__ y2p,
                float* __restrict__ out, int tilesPerBlk) {
  extern __shared__ char smem[];
  const int tid  = threadIdx.x;
  const int lane = tid & 63;
  const int wave = tid >> 6;       // 0..7 : w-col group (64 cols)
  const int l15  = lane & 15;
  const int lgr  = lane >> 4;      // 0..3
  const int arow = tid >> 3;       // stage row 0..63
  const int ag   = tid & 7;        // k-group (4 floats)

  float* xn2 = (float*)(smem + SCR);          // [64] (reused as tml)
  float* pS2 = (float*)(smem + SCR + 256);    // [64][8] (reused as pN2)
  float* pSB = (float*)(smem + SCR + 2304);   // [64][8]
  float* g12 = (float*)(smem + SCR + 4352);   // [64][2]

  // preload bias fragments + y2 (drained by prologue pack waits; used only in epilogue)
  f32x4 bvv[4];
#pragma unroll
  for (int nf = 0; nf < 4; ++nf)
    bvv[nf] = *(const f32x4*)(bexp + wave * 64 + nf * 16 + lgr * 4);
  float y2v = *y2p;

  f32x4 acc[4][4];
#pragma unroll
  for (int mf = 0; mf < 4; ++mf)
#pragma unroll
    for (int nf = 0; nf < 4; ++nf) acc[mf][nf] = f32x4{0.f, 0.f, 0.f, 0.f};

  const long tile0 = (long)blockIdx.x * tilesPerBlk;
  const int U = tilesPerBlk * 16;
  const float* xbase = x + (size_t)(tile0 * 64 + arow) * 512 + ag * 4;

  float xss = 0.f;
  f32x4 Lprev, Lcur;

  // ---- prologue: stage slices 0,1 of tile0 into slots 0,1 (compiler waits here
  //      drain the bvv/y2 loads too), then issue B(0) gloads ----
  {
    f32x4 a0 = *(const f32x4*)(xbase);
    f32x4 a1 = *(const f32x4*)(xbase + 32);
#pragma unroll
    for (int i = 0; i < 2; ++i) {
      f32x4 v = (i == 0) ? a0 : a1;
      xss += v[0] * v[0] + v[1] * v[1] + v[2] * v[2] + v[3] * v[3];
      uint2 pk;
      pk.x = (unsigned int)f2bf(v[0]) | ((unsigned int)f2bf(v[1]) << 16);
      pk.y = (unsigned int)f2bf(v[2]) | ((unsigned int)f2bf(v[3]) << 16);
      *(uint2*)(smem + i * ASLOT + arow * 72 + ag * 8) = pk;
    }
  }
#pragma unroll
  for (int r = 0; r < 4; ++r)
    GLD_LDS16((const char*)wsB + r * 8192 + wave * 1024 + lane * 16,
              smem + BOFF_L + r * 8192 + wave * 1024);
  LBAR();

#pragma unroll 1
  for (int u = 0; u < U; ++u) {
    // a) issue L(u): x data for global step u+2 (clamped dummy at tail)
    {
      int gu = u + 2; if (gu >= U) gu = 0;
      Lcur = *(const f32x4*)(xbase + (size_t)(gu >> 4) * 32768 + (gu & 15) * 32);
    }
    // b) issue B slice (u+1) into buf (u+1)&1 (fire-and-forget)
    {
      const char* bsrc = (const char*)wsB + (size_t)((u + 1) & 15) * 32768;
      char* bdst = smem + BOFF_L + ((u + 1) & 1) * 32768;
#pragma unroll
      for (int r = 0; r < 4; ++r)
        GLD_LDS16(bsrc + r * 8192 + wave * 1024 + lane * 16, bdst + r * 8192 + wave * 1024);
    }
    VMW5();    // drains [L(u-1), B(u)x4]; leaves [L(u), B(u+1)x4] in flight
    LBAR();

    // d) fragments + MFMA (swapped operands: D rows = w-cols)
    {
      const char* as = smem + (u & 3) * ASLOT + l15 * 72 + lgr * 16;
      const char* bb = smem + BOFF_L + (u & 1) * 32768 + (size_t)(wave * 4) * 1024 + lane * 16;
      bf16x8 xf[4], wf[4];
#pragma unroll
      for (int mf = 0; mf < 4; ++mf) xf[mf] = *(const bf16x8*)(as + mf * (16 * 72));
#pragma unroll
      for (int nf = 0; nf < 4; ++nf) wf[nf] = *(const bf16x8*)(bb + nf * 1024);
      __builtin_amdgcn_s_setprio(1);
#pragma unroll
      for (int mf = 0; mf < 4; ++mf)
#pragma unroll
        for (int nf = 0; nf < 4; ++nf)
          acc[mf][nf] = __builtin_amdgcn_mfma_f32_16x16x32_bf16(wf[nf], xf[mf], acc[mf][nf], 0, 0, 0);
      __builtin_amdgcn_s_setprio(0);
    }

    // ---- per-tile epilogue (before pack so xss is still this tile's) ----
    if ((u & 15) == 15) {
      const long trow = (tile0 + (u >> 4)) * 64;

      float xs = xss;
      xs += __shfl_xor(xs, 1); xs += __shfl_xor(xs, 2); xs += __shfl_xor(xs, 4);
      if ((lane & 7) == 0) xn2[wave * 8 + (lane >> 3)] = xs;
      xss = 0.f;

      float s2[4], sb[4];
#pragma unroll
      for (int mf = 0; mf < 4; ++mf) {
        s2[mf] = 0.f; sb[mf] = 0.f;
#pragma unroll
        for (int nf = 0; nf < 4; ++nf)
#pragma unroll
          for (int j = 0; j < 4; ++j) {
            float v = acc[mf][nf][j];
            s2[mf] += v * v;
            sb[mf] += v * bvv[nf][j];
          }
        s2[mf] += __shfl_xor(s2[mf], 16); s2[mf] += __shfl_xor(s2[mf], 32);
        sb[mf] += __shfl_xor(sb[mf], 16); sb[mf] += __shfl_xor(sb[mf], 32);
      }
      if (lane < 16) {
#pragma unroll
        for (int mf = 0; mf < 4; ++mf) {
          pS2[(mf * 16 + l15) * 8 + wave] = s2[mf];
          pSB[(mf * 16 + l15) * 8 + wave] = sb[mf];
        }
      }
      LBAR();

      if (tid < 64) {
        int r = tid;
        float S2 = 0.f, SB = 0.f;
#pragma unroll
        for (int i = 0; i < 8; ++i) { S2 += pS2[r * 8 + i]; SB += pSB[r * 8 + i]; }
        float xn  = fmaxf(sqrtf(xn2[r]), EPSV);
        float mxn = fmaxf(sqrtf(S2), EPSV);
        float f = tanhf((mxn / xn) * atanhf(fminf(xn, 1.f - EPSV))) / mxn;  // mv = f*mx
        float xy = f * SB;
        float x2 = f * f * S2;
        float den = 1.f + 2.f * xy + x2 * y2v + EPSV;
        float g1 = (1.f + 2.f * xy + y2v) * f / den;   // coeff on mx
        float g2 = (1.f - x2) / den;                   // coeff on b
        float n1sq = g1 * g1 * S2 + 2.f * g1 * g2 * SB + g2 * g2 * y2v;
        float n1 = fmaxf(sqrtf(fmaxf(n1sq, 0.f)), EPSV);
        if (n1 > 0.999f) { float sc = 0.999f / n1; g1 *= sc; g2 *= sc; }   // project()
        g12[r * 2] = g1; g12[r * 2 + 1] = g2;
      }
      LBAR();

      float n2p[4];
#pragma unroll
      for (int mf = 0; mf < 4; ++mf) {
        float g1 = g12[(mf * 16 + l15) * 2], g2 = g12[(mf * 16 + l15) * 2 + 1];
        n2p[mf] = 0.f;
#pragma unroll
        for (int nf = 0; nf < 4; ++nf)
#pragma unroll
          for (int j = 0; j < 4; ++j) {
            float v = g1 * acc[mf][nf][j] + g2 * bvv[nf][j];
            v = v > 0.f ? v : 0.2f * v;
            acc[mf][nf][j] = v;
            n2p[mf] += v * v;
          }
        n2p[mf] += __shfl_xor(n2p[mf], 16); n2p[mf] += __shfl_xor(n2p[mf], 32);
      }
      if (lane < 16) {
#pragma unroll
        for (int mf = 0; mf < 4; ++mf) pS2[(mf * 16 + l15) * 8 + wave] = n2p[mf];  // pN2
      }
      LBAR();

      if (tid < 64) {
        int r = tid;
        float sn = 0.f;
#pragma unroll
        for (int i = 0; i < 8; ++i) sn += pS2[r * 8 + i];
        float n2 = fmaxf(sqrtf(sn), EPSV);
        xn2[r] = tanhf(GAIN_R * atanhf(fminf(n2, 1.f - EPSV))) / n2;  // tml
      }
      LBAR();

      // store: 4 consecutive floats per lane per (mf,nf), direct from regs
#pragma unroll
      for (int mf = 0; mf < 4; ++mf) {
        float tm = xn2[mf * 16 + l15];
#pragma unroll
        for (int nf = 0; nf < 4; ++nf) {
          f32x4 o = acc[mf][nf];
          o[0] *= tm; o[1] *= tm; o[2] *= tm; o[3] *= tm;
          *(f32x4*)(out + (size_t)(trow + mf * 16 + l15) * 512 +
                    wave * 64 + nf * 16 + lgr * 4) = o;
          acc[mf][nf] = f32x4{0.f, 0.f, 0.f, 0.f};
        }
      }
    }

    // e) pack L(u-1) -> A-ring slot (u+1)&3 (data for step u+1)
    if (u > 0) {
      f32x4 v = Lprev;
      xss += v[0] * v[0] + v[1] * v[1] + v[2] * v[2] + v[3] * v[3];
      uint2 pk;
      pk.x = (unsigned int)f2bf(v[0]) | ((unsigned int)f2bf(v[1]) << 16);
      pk.y = (unsigned int)f2bf(v[2]) | ((unsigned int)f2bf(v[3]) << 16);
      *(uint2*)(smem + ((u + 1) & 3) * ASLOT + arow * 72 + ag * 8) = pk;
    }
    Lprev = Lcur;
    LBAR();
  }
}

extern "C" void kernel_launch(void* const* d_in, const int* in_sizes, int n_in,
                              void* d_out, int out_size, void* d_ws, size_t ws_size,
                              hipStream_t stream) {
  const float* x    = (const float*)d_in[0];
  const float* w    = (const float*)d_in[1];
  const float* bias = (const float*)d_in[2];
  float* out = (float*)d_out;

  unsigned short* wsB = (unsigned short*)d_ws;                 // 524288 B
  float* bexp = (float*)((char*)d_ws + 524288);                // 2048 B
  float* y2p  = (float*)((char*)d_ws + 524288 + 2048);         // 4 B

  bias_expmap_k<<<dim3(1), dim3(512), 0, stream>>>(bias, bexp, y2p);
  pack_weight_k<<<dim3(1024), dim3(256), 0, stream>>>(w, wsB);

  const int nrows  = in_sizes[0] / 512;      // 131072
  const int ntiles = nrows / 64;             // 2048
  const int nblk   = 256;                    // 1 block/CU, persistent
  const int tpb    = ntiles / nblk;          // 8
  hyp_main_k<<<dim3(nblk), dim3(512), SMEMSZ, stream>>>(x, wsB, bexp, y2p, out, tpb);
}

// Round 7
// 214.512 us; speedup vs baseline: 1.2325x; 1.2325x over previous
//
#include <hip/hip_runtime.h>
#include <math.h>

#define EPSV 1e-5f
#define SCALE_W 0.0441941738241592f   /* 1/sqrt(512) */
#define GAIN_R 1.4142135623730951f    /* sqrt(2) */

typedef __attribute__((ext_vector_type(8))) short bf16x8;
typedef __attribute__((ext_vector_type(4))) float f32x4;

static __device__ __forceinline__ unsigned short f2bf(float f) {
  union { float f; unsigned int u; } v; v.f = f;
  unsigned int r = v.u + 0x7FFFu + ((v.u >> 16) & 1u);   // RNE
  return (unsigned short)(r >> 16);
}

// lgkm-only barrier: does NOT drain vmcnt -> in-flight global loads survive
#define LBAR() do {                                          \
  asm volatile("s_waitcnt lgkmcnt(0)" ::: "memory");         \
  __builtin_amdgcn_sched_barrier(0);                         \
  __builtin_amdgcn_s_barrier();                              \
  __builtin_amdgcn_sched_barrier(0);                         \
} while (0)

// ---------------- pre-kernel: b = expmap0(bias), y2 = ||b||^2 ----------------
__global__ void bias_expmap_k(const float* __restrict__ bias, float* __restrict__ bexp,
                              float* __restrict__ y2out) {
  __shared__ float part[8];
  int t = threadIdx.x;
  float bv = bias[t];
  float s = bv * bv;
  s += __shfl_xor(s, 1);  s += __shfl_xor(s, 2);  s += __shfl_xor(s, 4);
  s += __shfl_xor(s, 8);  s += __shfl_xor(s, 16); s += __shfl_xor(s, 32);
  if ((t & 63) == 0) part[t >> 6] = s;
  __syncthreads();
  float tot = 0.f;
#pragma unroll
  for (int i = 0; i < 8; ++i) tot += part[i];
  float un = fmaxf(sqrtf(tot), EPSV);
  float th = tanhf(un);
  bexp[t] = th * bv / un;
  if (t == 0) *y2out = th * th;
}

// ---------------- pre-kernel: pack weight -> bf16 fragments, SCALE baked ----
__global__ void pack_weight_k(const float* __restrict__ w, unsigned short* __restrict__ wsB) {
  int e = blockIdx.x * 256 + threadIdx.x;   // 0..262143
  int o = e >> 9;          // output col (row of W)
  int k = e & 511;
  int ks = k >> 5, kk = k & 31;
  int lgr = kk >> 3, j = kk & 7;
  int colhi = o >> 4, l15 = o & 15;
  int dst = ((ks * 32 + colhi) * 64 + lgr * 16 + l15) * 8 + j;
  wsB[dst] = f2bf(w[e] * SCALE_W);
}

// ---------------- main fused kernel ----------------
// 512 thr (8 waves x 64 cols), BM=32 rows/tile, K in 2 halves of 8 ks (dbuf LDS).
// wf register double-buffer: B-fragments for ks+1 issued before MFMA(ks).
// Per-block k-rotation (8 within-half phases x half-swap) de-convoys the W stream.
#define RB 80
#define KSROW 2560       /* 32*80 */
#define BUFSZ 20480      /* 8*2560 */
#define SC_OFF 40960
#define SMEMSZ 43392

__global__ __launch_bounds__(512, 4)
void hyp_main_k(const float* __restrict__ x, const unsigned short* __restrict__ wsB,
                const float* __restrict__ bexp, const float* __restrict__ y2p,
                float* __restrict__ out, int tilesPerBlk) {
  extern __shared__ char smem[];
  const int tid  = threadIdx.x;
  const int lane = tid & 63;
  const int wave = tid >> 6;       // 0..7 : w-col group (64 cols each)
  const int l15  = lane & 15;
  const int lgr  = lane >> 4;      // 0..3
  const int srow = tid >> 4;       // stage row 0..31
  const int scol = tid & 15;
  const int rot   = blockIdx.x & 7;
  const int hswap = (blockIdx.x >> 3) & 1;

  float* xn2 = (float*)(smem + SC_OFF);          // [32] (reused as tml)
  float* pS2 = (float*)(smem + SC_OFF + 128);    // [32][8] (reused as pN2)
  float* pSB = (float*)(smem + SC_OFF + 1152);   // [32][8]
  float* g12 = (float*)(smem + SC_OFF + 2176);   // [32][2]

  f32x4 bv4[4];
#pragma unroll
  for (int nf = 0; nf < 4; ++nf) bv4[nf] = *(const f32x4*)(bexp + wave * 64 + nf * 16 + lgr * 4);

  f32x4 acc[2][4];
#pragma unroll
  for (int mf = 0; mf < 2; ++mf)
#pragma unroll
    for (int nf = 0; nf < 4; ++nf) acc[mf][nf] = f32x4{0.f, 0.f, 0.f, 0.f};

  const char* ard0 = smem + l15 * RB + lgr * 16;                         // + mf*1280 + ks*KSROW + buf
  const char* brd  = (const char*)wsB + ((wave * 4) * 64 + lane) * 16;   // + nf*1024 + gslice*32768
  char* awr0 = smem + srow * RB + (scol & 7) * 8;                        // + slice*KSROW + buf

  const long base = (long)blockIdx.x * tilesPerBlk;
  const int nss = 2 * tilesPerBlk;
  float xss = 0.f;
  f32x4 st[4];

  // ---- prologue: stage superstep 0 = half hswap of tile base ----
  {
    const float* p = x + (size_t)(base * 32 + srow) * 512 + hswap * 256 + scol * 4;
#pragma unroll
    for (int i = 0; i < 4; ++i) st[i] = *(const f32x4*)(p + i * 64);
#pragma unroll
    for (int i = 0; i < 4; ++i) {
      f32x4 v = st[i];
      xss += v[0] * v[0] + v[1] * v[1] + v[2] * v[2] + v[3] * v[3];
      uint2 pk;
      pk.x = (unsigned int)f2bf(v[0]) | ((unsigned int)f2bf(v[1]) << 16);
      pk.y = (unsigned int)f2bf(v[2]) | ((unsigned int)f2bf(v[3]) << 16);
      *(uint2*)(awr0 + (2 * i + (scol >> 3)) * KSROW) = pk;
    }
  }
  LBAR();

  for (int s = 0; s < nss; ++s) {
    const int h = s & 1;                 // 2nd superstep of tile?
    const int hcur = h ^ hswap;          // which K-half is staged
    const long tile = base + (s >> 1);
    const char* bufC = smem + (s & 1) * BUFSZ;
    const size_t hbase = (size_t)hcur * 8 * 32768;

    // ---- wf/xf preload for ks=0 (rotated) ----
    bf16x8 wfb[2][4], xfb[2][2];
    {
      const int g0 = rot;  // (0 + rot) & 7
#pragma unroll
      for (int r = 0; r < 4; ++r)
        wfb[0][r] = *(const bf16x8*)(brd + hbase + (size_t)g0 * 32768 + r * 1024);
    }

    // ---- issue-early: x-loads for superstep s+1 (in flight through K-loop) ----
    if (s + 1 < nss) {
      const int sp = s + 1;
      const float* p = x + (size_t)((base + (sp >> 1)) * 32 + srow) * 512 +
                       (((sp & 1) ^ hswap)) * 256 + scol * 4;
#pragma unroll
      for (int i = 0; i < 4; ++i) st[i] = *(const f32x4*)(p + i * 64);
    }

#pragma unroll
    for (int i = 0; i < 2; ++i)
      xfb[0][i] = *(const bf16x8*)(bufC + rot * KSROW + i * 1280 + (size_t)(ard0 - smem));

    // ---- K-loop (8 ks): register-dbuf'd wf, loads pinned before MFMA ----
#pragma unroll
    for (int ks = 0; ks < 8; ++ks) {
      const int cb = ks & 1, nb = cb ^ 1;
      if (ks < 7) {
        const int gn = (ks + 1 + rot) & 7;
#pragma unroll
        for (int r = 0; r < 4; ++r)
          wfb[nb][r] = *(const bf16x8*)(brd + hbase + (size_t)gn * 32768 + r * 1024);
#pragma unroll
        for (int i = 0; i < 2; ++i)
          xfb[nb][i] = *(const bf16x8*)(bufC + gn * KSROW + i * 1280 + (size_t)(ard0 - smem));
      }
      __builtin_amdgcn_sched_barrier(0);   // keep next-ks loads ahead of MFMA cluster
#pragma unroll
      for (int mf = 0; mf < 2; ++mf)
#pragma unroll
        for (int nf = 0; nf < 4; ++nf)
          acc[mf][nf] = __builtin_amdgcn_mfma_f32_16x16x32_bf16(wfb[cb][nf], xfb[cb][mf],
                                                                acc[mf][nf], 0, 0, 0);
    }

    // ---- epilogue at end of each tile (h==1) ----
    if (h == 1) {
      float xs = xss;
      xs += __shfl_xor(xs, 1); xs += __shfl_xor(xs, 2);
      xs += __shfl_xor(xs, 4); xs += __shfl_xor(xs, 8);
      if (scol == 0) xn2[srow] = xs;
      xss = 0.f;

      float s2[2] = {0.f, 0.f}, sb[2] = {0.f, 0.f};
#pragma unroll
      for (int mf = 0; mf < 2; ++mf)
#pragma unroll
        for (int nf = 0; nf < 4; ++nf)
#pragma unroll
          for (int j = 0; j < 4; ++j) {
            float v = acc[mf][nf][j];
            s2[mf] += v * v;
            sb[mf] += v * bv4[nf][j];
          }
#pragma unroll
      for (int mf = 0; mf < 2; ++mf) {
        s2[mf] += __shfl_xor(s2[mf], 16); s2[mf] += __shfl_xor(s2[mf], 32);
        sb[mf] += __shfl_xor(sb[mf], 16); sb[mf] += __shfl_xor(sb[mf], 32);
      }
      if (lane < 16) {
#pragma unroll
        for (int mf = 0; mf < 2; ++mf) {
          pS2[(mf * 16 + l15) * 8 + wave] = s2[mf];
          pSB[(mf * 16 + l15) * 8 + wave] = sb[mf];
        }
      }
      LBAR();

      if (tid < 32) {
        int r = tid;
        float S2 = 0.f, SB = 0.f;
#pragma unroll
        for (int i = 0; i < 8; ++i) { S2 += pS2[r * 8 + i]; SB += pSB[r * 8 + i]; }
        float y2 = *y2p;
        float xn  = fmaxf(sqrtf(xn2[r]), EPSV);
        float mxn = fmaxf(sqrtf(S2), EPSV);
        float f = tanhf((mxn / xn) * atanhf(fminf(xn, 1.f - EPSV))) / mxn;  // mv = f*mx
        float xy = f * SB;
        float x2 = f * f * S2;
        float den = 1.f + 2.f * xy + x2 * y2 + EPSV;
        float g1 = (1.f + 2.f * xy + y2) * f / den;   // coeff on mx
        float g2 = (1.f - x2) / den;                  // coeff on b
        float n1sq = g1 * g1 * S2 + 2.f * g1 * g2 * SB + g2 * g2 * y2;
        float n1 = fmaxf(sqrtf(fmaxf(n1sq, 0.f)), EPSV);
        if (n1 > 0.999f) { float sc = 0.999f / n1; g1 *= sc; g2 *= sc; }   // project()
        g12[r * 2] = g1; g12[r * 2 + 1] = g2;
      }
      LBAR();

      float n2p[2] = {0.f, 0.f};
#pragma unroll
      for (int mf = 0; mf < 2; ++mf) {
        float g1 = g12[(mf * 16 + l15) * 2], g2 = g12[(mf * 16 + l15) * 2 + 1];
#pragma unroll
        for (int nf = 0; nf < 4; ++nf)
#pragma unroll
          for (int j = 0; j < 4; ++j) {
            float v = g1 * acc[mf][nf][j] + g2 * bv4[nf][j];
            v = v > 0.f ? v : 0.2f * v;
            acc[mf][nf][j] = v;
            n2p[mf] += v * v;
          }
      }
#pragma unroll
      for (int mf = 0; mf < 2; ++mf) {
        n2p[mf] += __shfl_xor(n2p[mf], 16); n2p[mf] += __shfl_xor(n2p[mf], 32);
      }
      if (lane < 16) {
#pragma unroll
        for (int mf = 0; mf < 2; ++mf) pS2[(mf * 16 + l15) * 8 + wave] = n2p[mf];  // pN2
      }
      LBAR();

      if (tid < 32) {
        int r = tid;
        float sn = 0.f;
#pragma unroll
        for (int i = 0; i < 8; ++i) sn += pS2[r * 8 + i];
        float n2 = fmaxf(sqrtf(sn), EPSV);
        xn2[r] = tanhf(GAIN_R * atanhf(fminf(n2, 1.f - EPSV))) / n2;  // tml
      }
      LBAR();

      // store: 4 consecutive floats per lane per (mf,nf), direct from regs
#pragma unroll
      for (int mf = 0; mf < 2; ++mf) {
        float tm = xn2[mf * 16 + l15];
#pragma unroll
        for (int nf = 0; nf < 4; ++nf) {
          f32x4 o = acc[mf][nf];
          o[0] *= tm; o[1] *= tm; o[2] *= tm; o[3] *= tm;
          *(f32x4*)(out + (size_t)(tile * 32 + mf * 16 + l15) * 512 +
                    wave * 64 + nf * 16 + lgr * 4) = o;
          acc[mf][nf] = f32x4{0.f, 0.f, 0.f, 0.f};
        }
      }
    }

    // ---- write-late: convert staged regs -> LDS buf[(s+1)&1] ----
    if (s + 1 < nss) {
      char* awr = awr0 + ((s + 1) & 1) * BUFSZ;
#pragma unroll
      for (int i = 0; i < 4; ++i) {
        f32x4 v = st[i];
        xss += v[0] * v[0] + v[1] * v[1] + v[2] * v[2] + v[3] * v[3];
        uint2 pk;
        pk.x = (unsigned int)f2bf(v[0]) | ((unsigned int)f2bf(v[1]) << 16);
        pk.y = (unsigned int)f2bf(v[2]) | ((unsigned int)f2bf(v[3]) << 16);
        *(uint2*)(awr + (2 * i + (scol >> 3)) * KSROW) = pk;
      }
    }
    LBAR();
  }
}

extern "C" void kernel_launch(void* const* d_in, const int* in_sizes, int n_in,
                              void* d_out, int out_size, void* d_ws, size_t ws_size,
                              hipStream_t stream) {
  const float* x    = (const float*)d_in[0];
  const float* w    = (const float*)d_in[1];
  const float* bias = (const float*)d_in[2];
  float* out = (float*)d_out;

  unsigned short* wsB = (unsigned short*)d_ws;                 // 524288 B
  float* bexp = (float*)((char*)d_ws + 524288);                // 2048 B
  float* y2p  = (float*)((char*)d_ws + 524288 + 2048);         // 4 B

  bias_expmap_k<<<dim3(1), dim3(512), 0, stream>>>(bias, bexp, y2p);
  pack_weight_k<<<dim3(1024), dim3(256), 0, stream>>>(w, wsB);

  const int nrows  = in_sizes[0] / 512;      // 131072
  const int ntiles = nrows / 32;             // 4096
  const int nblk   = 1024;
  const int tpb    = ntiles / nblk;          // 4
  hyp_main_k<<<dim3(nblk), dim3(512), SMEMSZ, stream>>>(x, wsB, bexp, y2p, out, tpb);
}

// Round 8
// 177.160 us; speedup vs baseline: 1.4924x; 1.2108x over previous
//
#include <hip/hip_runtime.h>
#include <math.h>

#define EPSV 1e-5f
#define SCALE_W 0.0441941738241592f   /* 1/sqrt(512) */
#define GAIN_R 1.4142135623730951f    /* sqrt(2) */

typedef __attribute__((ext_vector_type(8))) short bf16x8;
typedef __attribute__((ext_vector_type(4))) float f32x4;
typedef __attribute__((ext_vector_type(4))) unsigned int u32x4;

static __device__ __forceinline__ unsigned short f2bf(float f) {
  union { float f; unsigned int u; } v; v.f = f;
  unsigned int r = v.u + 0x7FFFu + ((v.u >> 16) & 1u);   // RNE
  return (unsigned short)(r >> 16);
}

#define GLD_LDS16(gsrc, ldst)                                                                      \
  __builtin_amdgcn_global_load_lds((const __attribute__((address_space(1))) unsigned int*)(gsrc),  \
                                   (__attribute__((address_space(3))) unsigned int*)(ldst), 16, 0, 0)

// lgkm-only barrier: does NOT drain vmcnt -> in-flight loads/gload_lds survive
#define LBAR() do {                                          \
  asm volatile("s_waitcnt lgkmcnt(0)" ::: "memory");         \
  __builtin_amdgcn_sched_barrier(0);                         \
  __builtin_amdgcn_s_barrier();                              \
  __builtin_amdgcn_sched_barrier(0);                         \
} while (0)

#define VMCNT(N) do {                                        \
  asm volatile("s_waitcnt vmcnt(" #N ")" ::: "memory");      \
  __builtin_amdgcn_sched_barrier(0);                         \
} while (0)

// ---------------- pre-kernel: b = expmap0(bias), y2 = ||b||^2 ----------------
__global__ void bias_expmap_k(const float* __restrict__ bias, float* __restrict__ bexp,
                              float* __restrict__ y2out) {
  __shared__ float part[8];
  int t = threadIdx.x;
  float bv = bias[t];
  float s = bv * bv;
  s += __shfl_xor(s, 1);  s += __shfl_xor(s, 2);  s += __shfl_xor(s, 4);
  s += __shfl_xor(s, 8);  s += __shfl_xor(s, 16); s += __shfl_xor(s, 32);
  if ((t & 63) == 0) part[t >> 6] = s;
  __syncthreads();
  float tot = 0.f;
#pragma unroll
  for (int i = 0; i < 8; ++i) tot += part[i];
  float un = fmaxf(sqrtf(tot), EPSV);
  float th = tanhf(un);
  bexp[t] = th * bv / un;
  if (t == 0) *y2out = th * th;
}

// ---------------- pre-kernel: pack weight -> bf16 fragments, SCALE baked ----
// chunk = (ks*32 + colhi): 64 lanes x 16B; lane (lgr*16+l15) holds
// W[col=colhi*16+l15][k=ks*32+lgr*8+j], j=0..7.
__global__ void pack_weight_k(const float* __restrict__ w, unsigned short* __restrict__ wsB) {
  int e = blockIdx.x * 256 + threadIdx.x;   // 0..262143
  int o = e >> 9;          // output col (row of W)
  int k = e & 511;
  int ks = k >> 5, kk = k & 31;
  int lgr = kk >> 3, j = kk & 7;
  int colhi = o >> 4, l15 = o & 15;
  int dst = ((ks * 32 + colhi) * 64 + lgr * 16 + l15) * 8 + j;
  wsB[dst] = f2bf(w[e] * SCALE_W);
}

// ---------------- main fused kernel ----------------
// 256 thr / 4 waves, BM=64, BN=512, BK=32. Wave tile 64x128 (mf=4, nf=8).
// A: reg-staged fp32->bf16, dbuf [64 rows][80 B]. B: gload_lds dbuf 2x32KB.
// One lgkm barrier per K-step; counted vmcnt keeps 10 loads in flight.
#define RB 80
#define ABUF 5120        /* 64*80 */
#define BOFF 10240
#define BBUF 32768
#define SCR 75776
#define SMEMSZ 80896

__global__ __launch_bounds__(256, 2)
void hyp_main_k(const float* __restrict__ x, const unsigned short* __restrict__ wsB,
                const float* __restrict__ bexp, const float* __restrict__ y2p,
                float* __restrict__ out, int tilesPerBlk) {
  extern __shared__ char smem[];
  const int tid  = threadIdx.x;
  const int lane = tid & 63;
  const int wave = tid >> 6;       // 0..3 : col group (128 cols each)
  const int l15  = lane & 15;
  const int lgr  = lane >> 4;      // 0..3
  const int srow = tid >> 2;       // stage row 0..63
  const int sq   = tid & 3;        // k-subgroup (8 floats)

  float* xn2      = (float*)(smem + SCR);          // [64] (reused as tml)
  float* pS2      = (float*)(smem + SCR + 256);    // [64][4] (reused as pN2)
  float* pSB      = (float*)(smem + SCR + 1280);   // [64][4]
  float* g12      = (float*)(smem + SCR + 2304);   // [64][2]
  float* bexp_lds = (float*)(smem + SCR + 2816);   // [512]
  float* y2l      = (float*)(smem + SCR + 4864);   // [1]

  f32x4 acc[4][8];
#pragma unroll
  for (int mf = 0; mf < 4; ++mf)
#pragma unroll
    for (int nf = 0; nf < 8; ++nf) acc[mf][nf] = f32x4{0.f, 0.f, 0.f, 0.f};

  const long base = (long)blockIdx.x * tilesPerBlk;
  const int U = tilesPerBlk * 16;
  float xss = 0.f;
  f32x4 stA, stB;

  // ---- prologue ----
  {
    float2 bc = *(const float2*)(bexp + tid * 2);
    *(float2*)(bexp_lds + tid * 2) = bc;
    if (tid == 0) *y2l = *y2p;
    // A(0): rows base*64+srow, k = sq*8..sq*8+7
    const float* p = x + (size_t)(base * 64 + srow) * 512 + sq * 8;
    f32x4 a = *(const f32x4*)p;
    f32x4 b = *(const f32x4*)(p + 4);
    xss += a[0]*a[0] + a[1]*a[1] + a[2]*a[2] + a[3]*a[3];
    xss += b[0]*b[0] + b[1]*b[1] + b[2]*b[2] + b[3]*b[3];
    u32x4 pk;
    pk[0] = (unsigned int)f2bf(a[0]) | ((unsigned int)f2bf(a[1]) << 16);
    pk[1] = (unsigned int)f2bf(a[2]) | ((unsigned int)f2bf(a[3]) << 16);
    pk[2] = (unsigned int)f2bf(b[0]) | ((unsigned int)f2bf(b[1]) << 16);
    pk[3] = (unsigned int)f2bf(b[2]) | ((unsigned int)f2bf(b[3]) << 16);
    *(u32x4*)(smem + srow * RB + sq * 16) = pk;   // A buf 0
    // B(0) -> B buf 0 (queue after this: [B0 x8])
#pragma unroll
    for (int i = 0; i < 8; ++i)
      GLD_LDS16((const char*)wsB + (wave * 8 + i) * 1024 + lane * 16,
                smem + BOFF + (wave * 8 + i) * 1024);
  }
  LBAR();

#pragma unroll 1
  for (int t = 0; t < U; ++t) {
    const int cur = t & 1, nxt = cur ^ 1;

    // 1. issue A(t+1) loads (2)
    {
      const int gu = (t + 1 < U) ? t + 1 : U - 1;
      const float* p = x + (size_t)((base + (gu >> 4)) * 64 + srow) * 512 + (gu & 15) * 32 + sq * 8;
      stA = *(const f32x4*)p;
      stB = *(const f32x4*)(p + 4);
    }
    // 2. issue B(t+1) gloads (8) -> B buf nxt
    {
      const char* bs = (const char*)wsB + (size_t)((t + 1) & 15) * 32768;
      char* bd = smem + BOFF + nxt * BBUF;
#pragma unroll
      for (int i = 0; i < 8; ++i)
        GLD_LDS16(bs + (wave * 8 + i) * 1024 + lane * 16, bd + (wave * 8 + i) * 1024);
    }
    // 3. drain B(t) only (queue: [B(t)8][A(t+1)2 B(t+1)8]; +ST32 right after epilogue)
    if (t > 0 && (t & 15) == 0) { VMCNT(42); } else { VMCNT(10); }

    // 4. fragments + MFMA (swapped operands: store row = mf*16+l15)
    {
      const char* ab = smem + cur * ABUF + l15 * RB + lgr * 16;
      const char* bb = smem + BOFF + cur * BBUF + (wave * 8) * 1024 + lane * 16;
      bf16x8 xf[4], wf[8];
#pragma unroll
      for (int mf = 0; mf < 4; ++mf) xf[mf] = *(const bf16x8*)(ab + mf * (16 * RB));
#pragma unroll
      for (int nf = 0; nf < 8; ++nf) wf[nf] = *(const bf16x8*)(bb + nf * 1024);
      __builtin_amdgcn_s_setprio(1);
#pragma unroll
      for (int mf = 0; mf < 4; ++mf)
#pragma unroll
        for (int nf = 0; nf < 8; ++nf)
          acc[mf][nf] = __builtin_amdgcn_mfma_f32_16x16x32_bf16(wf[nf], xf[mf], acc[mf][nf], 0, 0, 0);
      __builtin_amdgcn_s_setprio(0);
    }

    // 5. fused hyperbolic epilogue (before pack: xss is still this tile's)
    if ((t & 15) == 15) {
      const long trow = (base + (t >> 4)) * 64;

      float xs = xss;
      xs += __shfl_xor(xs, 1); xs += __shfl_xor(xs, 2);
      if (sq == 0) xn2[srow] = xs;
      xss = 0.f;

      f32x4 bvv[8];
#pragma unroll
      for (int nf = 0; nf < 8; ++nf)
        bvv[nf] = *(const f32x4*)(bexp_lds + wave * 128 + nf * 16 + lgr * 4);
      const float y2 = *y2l;

      float s2[4], sb[4];
#pragma unroll
      for (int mf = 0; mf < 4; ++mf) {
        s2[mf] = 0.f; sb[mf] = 0.f;
#pragma unroll
        for (int nf = 0; nf < 8; ++nf)
#pragma unroll
          for (int j = 0; j < 4; ++j) {
            float v = acc[mf][nf][j];
            s2[mf] += v * v;
            sb[mf] += v * bvv[nf][j];
          }
        s2[mf] += __shfl_xor(s2[mf], 16); s2[mf] += __shfl_xor(s2[mf], 32);
        sb[mf] += __shfl_xor(sb[mf], 16); sb[mf] += __shfl_xor(sb[mf], 32);
      }
      if (lane < 16) {
#pragma unroll
        for (int mf = 0; mf < 4; ++mf) {
          pS2[(mf * 16 + l15) * 4 + wave] = s2[mf];
          pSB[(mf * 16 + l15) * 4 + wave] = sb[mf];
        }
      }
      LBAR();

      if (tid < 64) {
        int r = tid;
        float S2 = 0.f, SB = 0.f;
#pragma unroll
        for (int i = 0; i < 4; ++i) { S2 += pS2[r * 4 + i]; SB += pSB[r * 4 + i]; }
        float y2s = *y2l;
        float xn  = fmaxf(sqrtf(xn2[r]), EPSV);
        float mxn = fmaxf(sqrtf(S2), EPSV);
        float f = tanhf((mxn / xn) * atanhf(fminf(xn, 1.f - EPSV))) / mxn;  // mv = f*mx
        float xy = f * SB;
        float x2 = f * f * S2;
        float den = 1.f + 2.f * xy + x2 * y2s + EPSV;
        float g1 = (1.f + 2.f * xy + y2s) * f / den;   // coeff on mx
        float g2 = (1.f - x2) / den;                   // coeff on b
        float n1sq = g1 * g1 * S2 + 2.f * g1 * g2 * SB + g2 * g2 * y2s;
        float n1 = fmaxf(sqrtf(fmaxf(n1sq, 0.f)), EPSV);
        if (n1 > 0.999f) { float sc = 0.999f / n1; g1 *= sc; g2 *= sc; }   // project()
        g12[r * 2] = g1; g12[r * 2 + 1] = g2;
      }
      LBAR();

      float n2p[4];
#pragma unroll
      for (int mf = 0; mf < 4; ++mf) {
        float g1 = g12[(mf * 16 + l15) * 2], g2 = g12[(mf * 16 + l15) * 2 + 1];
        n2p[mf] = 0.f;
#pragma unroll
        for (int nf = 0; nf < 8; ++nf)
#pragma unroll
          for (int j = 0; j < 4; ++j) {
            float v = g1 * acc[mf][nf][j] + g2 * bvv[nf][j];
            v = v > 0.f ? v : 0.2f * v;
            acc[mf][nf][j] = v;
            n2p[mf] += v * v;
          }
        n2p[mf] += __shfl_xor(n2p[mf], 16); n2p[mf] += __shfl_xor(n2p[mf], 32);
      }
      if (lane < 16) {
#pragma unroll
        for (int mf = 0; mf < 4; ++mf) pS2[(mf * 16 + l15) * 4 + wave] = n2p[mf];  // pN2
      }
      LBAR();

      if (tid < 64) {
        int r = tid;
        float sn = 0.f;
#pragma unroll
        for (int i = 0; i < 4; ++i) sn += pS2[r * 4 + i];
        float n2 = fmaxf(sqrtf(sn), EPSV);
        xn2[r] = tanhf(GAIN_R * atanhf(fminf(n2, 1.f - EPSV))) / n2;  // tml
      }
      LBAR();

      // stores (32 x 16B per thread; they enter the vmcnt queue -> ledger below)
#pragma unroll
      for (int mf = 0; mf < 4; ++mf) {
        float tm = xn2[mf * 16 + l15];
#pragma unroll
        for (int nf = 0; nf < 8; ++nf) {
          f32x4 o = acc[mf][nf];
          o[0] *= tm; o[1] *= tm; o[2] *= tm; o[3] *= tm;
          *(f32x4*)(out + (size_t)(trow + mf * 16 + l15) * 512 +
                    wave * 128 + nf * 16 + lgr * 4) = o;
          acc[mf][nf] = f32x4{0.f, 0.f, 0.f, 0.f};
        }
      }
    }

    // 6. drain A(t+1) only (epilogue steps: +32 stores in queue ahead of nothing-needed)
    if ((t & 15) == 15) { VMCNT(40); } else { VMCNT(8); }

    // pack + ds_write A(t+1) -> A buf nxt
    {
      f32x4 a = stA, b = stB;
      xss += a[0]*a[0] + a[1]*a[1] + a[2]*a[2] + a[3]*a[3];
      xss += b[0]*b[0] + b[1]*b[1] + b[2]*b[2] + b[3]*b[3];
      u32x4 pk;
      pk[0] = (unsigned int)f2bf(a[0]) | ((unsigned int)f2bf(a[1]) << 16);
      pk[1] = (unsigned int)f2bf(a[2]) | ((unsigned int)f2bf(a[3]) << 16);
      pk[2] = (unsigned int)f2bf(b[0]) | ((unsigned int)f2bf(b[1]) << 16);
      pk[3] = (unsigned int)f2bf(b[2]) | ((unsigned int)f2bf(b[3]) << 16);
      *(u32x4*)(smem + nxt * ABUF + srow * RB + sq * 16) = pk;
    }
    // 7.
    LBAR();
  }
}

extern "C" void kernel_launch(void* const* d_in, const int* in_sizes, int n_in,
                              void* d_out, int out_size, void* d_ws, size_t ws_size,
                              hipStream_t stream) {
  const float* x    = (const float*)d_in[0];
  const float* w    = (const float*)d_in[1];
  const float* bias = (const float*)d_in[2];
  float* out = (float*)d_out;

  unsigned short* wsB = (unsigned short*)d_ws;                 // 524288 B
  float* bexp = (float*)((char*)d_ws + 524288);                // 2048 B
  float* y2p  = (float*)((char*)d_ws + 524288 + 2048);         // 4 B

  bias_expmap_k<<<dim3(1), dim3(512), 0, stream>>>(bias, bexp, y2p);
  pack_weight_k<<<dim3(1024), dim3(256), 0, stream>>>(w, wsB);

  const int nrows  = in_sizes[0] / 512;      // 131072
  const int ntiles = nrows / 64;             // 2048
  const int nblk   = 512;                    // 2 blocks/CU, persistent
  const int tpb    = ntiles / nblk;          // 4
  hyp_main_k<<<dim3(nblk), dim3(256), SMEMSZ, stream>>>(x, wsB, bexp, y2p, out, tpb);
}